// Round 2
// baseline (273.653 us; speedup 1.0000x reference)
//
#include <hip/hip_runtime.h>
#include <hip/hip_bf16.h>
#include <hip/hip_fp16.h>

// Bahdanau location-sensitive attention, fused f16-MFMA implementation.
// R2: k_main rewritten as 256x256-tile, reg-staged, single-barrier-per-K-step
//     pipelined GEMM (T3-style) + T5 setprio + bijective XCD swizzle.
// B=32 T=1536 H=1024 CTX=1024 CONV_OUT=32

constexpr int kB = 32, kT = 1536, kH = 1024, kC = 1024, kCO = 32;
constexpr int kM = kB * kT;      // 49152
constexpr int kK = kH + kCO;     // 1056

typedef _Float16 f16;
typedef _Float16 f16x8 __attribute__((ext_vector_type(8)));
typedef float f32x4 __attribute__((ext_vector_type(4)));

// ---- ws layout (bytes) ----
constexpr size_t WS_BF16  = 0;                                  // kC*kK f16   (2.2 MB)
constexpr size_t WS_LOC   = WS_BF16 + (size_t)kC * kK * 2;      // kM*kCO f16  (3 MB)
constexpr size_t WS_ADD   = WS_LOC + (size_t)kM * kCO * 2;      // kB*kC f32
constexpr size_t WS_SCORE = WS_ADD + (size_t)kB * kC * 4;       // 4*kM f32 partial scores
constexpr size_t WS_CTXP  = WS_SCORE + (size_t)4 * kM * 4;      // 8*kB*kH f32

// ---------------------------------------------------------------- prep B
__global__ void k_prep_b(const float* __restrict__ V, const float* __restrict__ U,
                         f16* __restrict__ Bf) {
    int idx = blockIdx.x * 256 + threadIdx.x;        // < kC*kK
    int c = idx / kK, k = idx - c * kK;
    float v = (k < kH) ? V[(size_t)c * kH + k] : U[(size_t)c * kCO + (k - kH)];
    Bf[idx] = (f16)v;
}

// ---------------------------------------------------------------- prep loc (conv1d)
__global__ void k_prep_loc(const float* __restrict__ la, const float* __restrict__ cw,
                           const float* __restrict__ cb, f16* __restrict__ loc) {
    int m = blockIdx.x * 256 + threadIdx.x;          // < kM
    int b = m / kT, t = m - b * kT;
    float x0 = (t > 0)      ? la[(size_t)b * kT + t - 1] : 0.f;
    float x1 = la[(size_t)b * kT + t];
    float x2 = (t < kT - 1) ? la[(size_t)b * kT + t + 1] : 0.f;
    union { f16 h[32]; int4 q[4]; } u;
#pragma unroll
    for (int k = 0; k < 32; ++k)
        u.h[k] = (f16)(cw[k * 3] * x0 + cw[k * 3 + 1] * x1 + cw[k * 3 + 2] * x2 + cb[k]);
    int4* dst = (int4*)(loc + (size_t)m * 32);
    dst[0] = u.q[0]; dst[1] = u.q[1]; dst[2] = u.q[2]; dst[3] = u.q[3];
}

// ---------------------------------------------------------------- prep add = dec@W^T + bias
__global__ void k_prep_add(const float* __restrict__ dec, const float* __restrict__ W,
                           const float* __restrict__ bias, float* __restrict__ add) {
    __shared__ float dl[kH];
    int bb = blockIdx.x >> 2;
    int cc = (blockIdx.x & 3) * 256 + threadIdx.x;
    *(float4*)&dl[threadIdx.x * 4] = *(const float4*)&dec[(size_t)bb * kH + threadIdx.x * 4];
    __syncthreads();
    float acc = bias[cc];
    const float* wr = W + (size_t)cc * kH;
    for (int h = 0; h < kH; h += 4) {
        float4 wv = *(const float4*)&wr[h];
        acc += wv.x * dl[h] + wv.y * dl[h + 1] + wv.z * dl[h + 2] + wv.w * dl[h + 3];
    }
    add[(size_t)bb * kC + cc] = acc;
}

// ---------------------------------------------------------------- fused main GEMM
// tile 256(M) x 256(N), 512 threads = 8 waves (2 x 4), per-wave 128x64, BK=64.
// Reg-staged pipeline: issue loads(t+1) -> compute(t) [2 kk-phases, setprio] ->
// cvt+ds_write(t+1) -> ONE __syncthreads per K-step. LDS dbuf, XOR-swizzled
// rows (slot ^= row&7 within the 8x16B slots of each 128B row).
__launch_bounds__(512, 2)
__global__ void k_main(const float* __restrict__ enc, const f16* __restrict__ Bf,
                       const f16* __restrict__ loc, const float* __restrict__ add,
                       const float* __restrict__ wvec, float* __restrict__ spart) {
    // LDS: As[2][256*64 f16] @0 (2x32KB), Bs[2][...] @65536, add_l @131072, w_l @132096
    // sred aliases Bs[1] (@98304) — Bs[1] is dead by epilogue time.
    __shared__ __align__(16) char smem[133120];
    float* add_l = (float*)(smem + 131072);
    float* w_l   = (float*)(smem + 132096);

    const int tid = threadIdx.x, lane = tid & 63, wave = tid >> 6;
    const int wm = wave >> 2, wn = wave & 3;
    // bijective XCD-chunked swizzle: 768 blocks, 8 XCDs, 96 blocks/XCD.
    const int raw = blockIdx.x;
    const int swz = (raw & 7) * 96 + (raw >> 3);
    const int mt = swz >> 2, nt = swz & 3;           // nt fastest: A strip shared in-XCD
    const int m0 = mt * 256, n0 = nt * 256;
    const int bb = m0 / kT;                          // 1536 % 256 == 0: one batch per tile

    if (tid < 256) {
        add_l[tid] = add[(size_t)bb * kC + n0 + tid];
        w_l[tid]   = wvec[n0 + tid];
    }

    f32x4 acc[8][4];
#pragma unroll
    for (int i = 0; i < 8; ++i)
#pragma unroll
        for (int j = 0; j < 4; ++j) acc[i][j] = (f32x4){0.f, 0.f, 0.f, 0.f};

    // staging: 2 threads per row, 512 threads cover 256 rows x 64 K
    const int srow = tid >> 1, shalf = tid & 1, sxm = srow & 7;
    const float* a_src  = enc + (size_t)(m0 + srow) * kH + shalf * 32;
    const f16*   b_src  = Bf  + (size_t)(n0 + srow) * kK + shalf * 32;
    const f16*   l_src  = loc + (size_t)(m0 + srow) * kCO + shalf * 16;
    const f16*   bt_src = Bf  + (size_t)(n0 + srow) * kK + kH + shalf * 16;

    float4 a_ld[8]; int4 b_ld[4];
    int4 ta0, ta1, tb0, tb1;

    // ---- prologue: stage tile 0 into buf 0
#pragma unroll
    for (int q = 0; q < 8; ++q) a_ld[q] = *(const float4*)(a_src + q * 4);
#pragma unroll
    for (int j = 0; j < 4; ++j) b_ld[j] = *(const int4*)(b_src + j * 8);
    {
        union { f16 h[32]; int4 q[4]; } pk;
#pragma unroll
        for (int q = 0; q < 8; ++q) {
            pk.h[q * 4 + 0] = (f16)a_ld[q].x; pk.h[q * 4 + 1] = (f16)a_ld[q].y;
            pk.h[q * 4 + 2] = (f16)a_ld[q].z; pk.h[q * 4 + 3] = (f16)a_ld[q].w;
        }
        char* Aw = smem + srow * 128;
        char* Bw = smem + 65536 + srow * 128;
#pragma unroll
        for (int j = 0; j < 4; ++j) {
            int sl = ((shalf * 4 + j) ^ sxm) * 16;
            *(int4*)(Aw + sl) = pk.q[j];
            *(int4*)(Bw + sl) = b_ld[j];
        }
    }
    __syncthreads();

    // ---- main loop: 16 full K-steps (enc), tail staged at t==15
    for (int t = 0; t < 16; ++t) {
        const int cur = t & 1;
        if (t < 15) {                      // issue loads for tile t+1 (in flight across compute)
            const int k0 = (t + 1) * 64;
#pragma unroll
            for (int q = 0; q < 8; ++q) a_ld[q] = *(const float4*)(a_src + k0 + q * 4);
#pragma unroll
            for (int j = 0; j < 4; ++j) b_ld[j] = *(const int4*)(b_src + k0 + j * 8);
        } else {                           // tail tile: loc (f16) + U columns of Bf
            ta0 = *(const int4*)(l_src);
            ta1 = *(const int4*)(l_src + 8);
            tb0 = *(const int4*)(bt_src);
            tb1 = *(const int4*)(bt_src + 8);
        }

        const char* Ac = smem + cur * 32768;
        const char* Bc = smem + 65536 + cur * 32768;
        const int g = lane >> 4, rl = lane & 15;
#pragma unroll
        for (int kk = 0; kk < 2; ++kk) {
            f16x8 af[8], bfv[4];
#pragma unroll
            for (int mi = 0; mi < 8; ++mi) {
                int row = wm * 128 + mi * 16 + rl;
                af[mi] = *(const f16x8*)(Ac + row * 128 + (((kk * 4 + g) ^ (row & 7)) * 16));
            }
#pragma unroll
            for (int ni = 0; ni < 4; ++ni) {
                int row = wn * 64 + ni * 16 + rl;
                bfv[ni] = *(const f16x8*)(Bc + row * 128 + (((kk * 4 + g) ^ (row & 7)) * 16));
            }
            __builtin_amdgcn_s_setprio(1);
#pragma unroll
            for (int mi = 0; mi < 8; ++mi)
#pragma unroll
                for (int ni = 0; ni < 4; ++ni)
                    acc[mi][ni] = __builtin_amdgcn_mfma_f32_16x16x32_f16(af[mi], bfv[ni], acc[mi][ni], 0, 0, 0);
            __builtin_amdgcn_s_setprio(0);
        }

        // stage tile t+1 into buf cur^1 (loads consumed here, right before barrier)
        char* Aw = smem + (cur ^ 1) * 32768 + srow * 128;
        char* Bw = smem + 65536 + (cur ^ 1) * 32768 + srow * 128;
        if (t < 15) {
            union { f16 h[32]; int4 q[4]; } pk;
#pragma unroll
            for (int q = 0; q < 8; ++q) {
                pk.h[q * 4 + 0] = (f16)a_ld[q].x; pk.h[q * 4 + 1] = (f16)a_ld[q].y;
                pk.h[q * 4 + 2] = (f16)a_ld[q].z; pk.h[q * 4 + 3] = (f16)a_ld[q].w;
            }
#pragma unroll
            for (int j = 0; j < 4; ++j) {
                int sl = ((shalf * 4 + j) ^ sxm) * 16;
                *(int4*)(Aw + sl) = pk.q[j];
                *(int4*)(Bw + sl) = b_ld[j];
            }
        } else {
            *(int4*)(Aw + (((shalf * 2 + 0) ^ sxm) * 16)) = ta0;
            *(int4*)(Aw + (((shalf * 2 + 1) ^ sxm) * 16)) = ta1;
            *(int4*)(Bw + (((shalf * 2 + 0) ^ sxm) * 16)) = tb0;
            *(int4*)(Bw + (((shalf * 2 + 1) ^ sxm) * 16)) = tb1;
        }
        __syncthreads();
    }

    // ---- tail compute: buf 0, K=32 (slots 0..3 pre-xor)
    {
        const char* Ac = smem;
        const char* Bc = smem + 65536;
        const int g = lane >> 4, rl = lane & 15;
        f16x8 af[8], bfv[4];
#pragma unroll
        for (int mi = 0; mi < 8; ++mi) {
            int row = wm * 128 + mi * 16 + rl;
            af[mi] = *(const f16x8*)(Ac + row * 128 + ((g ^ (row & 7)) * 16));
        }
#pragma unroll
        for (int ni = 0; ni < 4; ++ni) {
            int row = wn * 64 + ni * 16 + rl;
            bfv[ni] = *(const f16x8*)(Bc + row * 128 + ((g ^ (row & 7)) * 16));
        }
        __builtin_amdgcn_s_setprio(1);
#pragma unroll
        for (int mi = 0; mi < 8; ++mi)
#pragma unroll
            for (int ni = 0; ni < 4; ++ni)
                acc[mi][ni] = __builtin_amdgcn_mfma_f32_16x16x32_f16(af[mi], bfv[ni], acc[mi][ni], 0, 0, 0);
        __builtin_amdgcn_s_setprio(0);
    }

    // ---- epilogue: e = tanh(acc + add[c]); partial score = sum_c e*w[c]
    float (*sred)[128][4] = (float (*)[128][4])(smem + 98304);  // aliases Bs[1] (dead)
    {
        const int rl = lane & 15, gq = lane >> 4;
#pragma unroll
        for (int mi = 0; mi < 8; ++mi) {
#pragma unroll
            for (int i = 0; i < 4; ++i) {
                float p = 0.f;
#pragma unroll
                for (int ni = 0; ni < 4; ++ni) {
                    int cl = wn * 64 + ni * 16 + rl;
                    float e = tanhf(acc[mi][ni][i] + add_l[cl]);
                    p += e * w_l[cl];
                }
                p += __shfl_xor(p, 1);
                p += __shfl_xor(p, 2);
                p += __shfl_xor(p, 4);
                p += __shfl_xor(p, 8);
                if (rl == 0) sred[wm][mi * 16 + gq * 4 + i][wn] = p;
            }
        }
    }
    __syncthreads();
    if (tid < 256) {
        float s = sred[tid >> 7][tid & 127][0] + sred[tid >> 7][tid & 127][1]
                + sred[tid >> 7][tid & 127][2] + sred[tid >> 7][tid & 127][3];
        spart[(size_t)nt * kM + m0 + tid] = s;
    }
}

// ---------------------------------------------------------------- softmax over T
__global__ void k_softmax(const float* __restrict__ spart, float* __restrict__ out_align) {
    __shared__ float red[256];
    int b = blockIdx.x, tid = threadIdx.x;
    float v[6];
    float mx = -1e30f;
#pragma unroll
    for (int i = 0; i < 6; ++i) {
        size_t idx = (size_t)b * kT + tid + i * 256;
        float s = spart[idx] + spart[kM + idx] + spart[2 * (size_t)kM + idx] + spart[3 * (size_t)kM + idx];
        v[i] = s; mx = fmaxf(mx, s);
    }
    red[tid] = mx; __syncthreads();
    for (int o = 128; o > 0; o >>= 1) { if (tid < o) red[tid] = fmaxf(red[tid], red[tid + o]); __syncthreads(); }
    mx = red[0]; __syncthreads();
    float sum = 0.f;
#pragma unroll
    for (int i = 0; i < 6; ++i) { v[i] = expf(v[i] - mx); sum += v[i]; }
    red[tid] = sum; __syncthreads();
    for (int o = 128; o > 0; o >>= 1) { if (tid < o) red[tid] += red[tid + o]; __syncthreads(); }
    float inv = 1.f / red[0];
#pragma unroll
    for (int i = 0; i < 6; ++i)
        out_align[(size_t)b * kT + tid + i * 256] = v[i] * inv;
}

// ---------------------------------------------------------------- context partials
__global__ void k_ctx_part(const float* __restrict__ enc, const float* __restrict__ align,
                           float* __restrict__ cpart) {
    __shared__ float al[192];
    int ci = blockIdx.x, b = blockIdx.y, tid = threadIdx.x;
    if (tid < 192) al[tid] = align[(size_t)b * kT + ci * 192 + tid];
    __syncthreads();
    float4 acc = {0.f, 0.f, 0.f, 0.f};
    const float* ep = enc + ((size_t)b * kT + (size_t)ci * 192) * kH + tid * 4;
    for (int t = 0; t < 192; ++t) {
        float a = al[t];
        float4 e = *(const float4*)(ep + (size_t)t * kH);
        acc.x += a * e.x; acc.y += a * e.y; acc.z += a * e.z; acc.w += a * e.w;
    }
    *(float4*)&cpart[((size_t)ci * kB + b) * kH + tid * 4] = acc;
}

__global__ void k_ctx_red(const float* __restrict__ cpart, float* __restrict__ out_ctx) {
    int idx = blockIdx.x * 256 + threadIdx.x;   // < kB*kH
    float s = 0.f;
#pragma unroll
    for (int ci = 0; ci < 8; ++ci) s += cpart[(size_t)ci * kB * kH + idx];
    out_ctx[idx] = s;
}

// ---------------------------------------------------------------- launch
extern "C" void kernel_launch(void* const* d_in, const int* in_sizes, int n_in,
                              void* d_out, int out_size, void* d_ws, size_t ws_size,
                              hipStream_t stream) {
    const float* dec  = (const float*)d_in[0];
    const float* enc  = (const float*)d_in[1];
    const float* la   = (const float*)d_in[2];
    const float* W    = (const float*)d_in[3];
    const float* V    = (const float*)d_in[4];
    const float* U    = (const float*)d_in[5];
    const float* bias = (const float*)d_in[6];
    const float* wv   = (const float*)d_in[7];
    const float* cw   = (const float*)d_in[8];
    const float* cb   = (const float*)d_in[9];

    char* ws = (char*)d_ws;
    f16* Bf      = (f16*)(ws + WS_BF16);
    f16* loc     = (f16*)(ws + WS_LOC);
    float* add   = (float*)(ws + WS_ADD);
    float* spart = (float*)(ws + WS_SCORE);
    float* cpart = (float*)(ws + WS_CTXP);

    float* out_ctx   = (float*)d_out;            // (B,H)
    float* out_align = (float*)d_out + kB * kH;  // (B,T)

    hipLaunchKernelGGL(k_prep_b,   dim3(kC * kK / 256), dim3(256), 0, stream, V, U, Bf);
    hipLaunchKernelGGL(k_prep_loc, dim3(kM / 256),      dim3(256), 0, stream, la, cw, cb, loc);
    hipLaunchKernelGGL(k_prep_add, dim3(kB * 4),        dim3(256), 0, stream, dec, W, bias, add);
    hipLaunchKernelGGL(k_main,     dim3((kM / 256) * 4), dim3(512), 0, stream, enc, Bf, loc, add, wv, spart);
    hipLaunchKernelGGL(k_softmax,  dim3(kB),            dim3(256), 0, stream, spart, out_align);
    hipLaunchKernelGGL(k_ctx_part, dim3(8, kB),         dim3(256), 0, stream, enc, out_align, cpart);
    hipLaunchKernelGGL(k_ctx_red,  dim3(kB * kH / 256), dim3(256), 0, stream, cpart, out_ctx);
}